// Round 1
// baseline (282.697 us; speedup 1.0000x reference)
//
#include <hip/hip_runtime.h>

// 10-qubit batched statevector simulator.
// One wave (64 lanes) per sample; state = 16 complex amps/lane in VGPRs.
// Bit p of amplitude index: p in 0..5 -> lane bit p ; p in 6..9 -> register bit p-6.
// Qubit q (PennyLane wire, MSB-first) lives at bit p = 9 - q.

namespace {

constexpr int NQB = 10;

template<int P>
__device__ __forceinline__ void rot_gate(float (&sr)[16], float (&si)[16],
                                         const float* m, int lane) {
  const float u00r = m[0], u00i = m[1], u01r = m[2], u01i = m[3];
  const float u10r = m[4], u10i = m[5], u11r = m[6], u11i = m[7];
  if constexpr (P >= 6) {
    constexpr int J = 1 << (P - 6);
#pragma unroll
    for (int r0 = 0; r0 < 16; ++r0) {
      if (r0 & J) continue;
      const int r1 = r0 | J;
      const float a0r = sr[r0], a0i = si[r0];
      const float a1r = sr[r1], a1i = si[r1];
      sr[r0] = u00r*a0r - u00i*a0i + u01r*a1r - u01i*a1i;
      si[r0] = u00r*a0i + u00i*a0r + u01r*a1i + u01i*a1r;
      sr[r1] = u10r*a0r - u10i*a0i + u11r*a1r - u11i*a1i;
      si[r1] = u10r*a0i + u10i*a0r + u11r*a1i + u11i*a1r;
    }
  } else {
    const int bit = (lane >> P) & 1;
    // own-coefficient / partner-coefficient selected by this lane's bit value
    const float uar = bit ? u11r : u00r;
    const float uai = bit ? u11i : u00i;
    const float ubr = bit ? u10r : u01r;
    const float ubi = bit ? u10i : u01i;
#pragma unroll
    for (int r = 0; r < 16; ++r) {
      const float pr = __shfl_xor(sr[r], 1 << P, 64);
      const float pq = __shfl_xor(si[r], 1 << P, 64);
      const float ar = sr[r], ai = si[r];
      sr[r] = uar*ar - uai*ai + ubr*pr - ubi*pq;
      si[r] = uar*ai + uai*ar + ubr*pq + ubi*pr;
    }
  }
}

template<int PC, int PT>
__device__ __forceinline__ void cry_gate(float (&sr)[16], float (&si)[16],
                                         float c, float s, int lane) {
  if constexpr (PT >= 6) {
    constexpr int J = 1 << (PT - 6);
    if constexpr (PC >= 6) {
      constexpr int CB = 1 << (PC - 6);
#pragma unroll
      for (int r0 = 0; r0 < 16; ++r0) {
        if ((r0 & J) || !(r0 & CB)) continue;   // need control bit = 1, target bit = 0
        const int r1 = r0 | J;
        const float a0r = sr[r0], a0i = si[r0];
        const float a1r = sr[r1], a1i = si[r1];
        sr[r0] = c*a0r - s*a1r;  si[r0] = c*a0i - s*a1i;
        sr[r1] = s*a0r + c*a1r;  si[r1] = s*a0i + c*a1i;
      }
    } else {
      const bool ctrl = (lane >> PC) & 1;
#pragma unroll
      for (int r0 = 0; r0 < 16; ++r0) {
        if (r0 & J) continue;
        const int r1 = r0 | J;
        const float a0r = sr[r0], a0i = si[r0];
        const float a1r = sr[r1], a1i = si[r1];
        const float n0r = c*a0r - s*a1r, n0i = c*a0i - s*a1i;
        const float n1r = s*a0r + c*a1r, n1i = s*a0i + c*a1i;
        sr[r0] = ctrl ? n0r : a0r;  si[r0] = ctrl ? n0i : a0i;
        sr[r1] = ctrl ? n1r : a1r;  si[r1] = ctrl ? n1i : a1i;
      }
    }
  } else {
    // target is a lane bit: partner lane = lane ^ (1<<PT); control bit identical
    // on both partner lanes, so the shuffle is safely executed by all lanes.
    const int tbit = (lane >> PT) & 1;
    const float ss = tbit ? s : -s;   // bit0: c*a0 - s*a1 ; bit1: c*a1 + s*a0
    if constexpr (PC >= 6) {
      constexpr int CB = 1 << (PC - 6);
#pragma unroll
      for (int r = 0; r < 16; ++r) {
        if (!(r & CB)) continue;
        const float pr = __shfl_xor(sr[r], 1 << PT, 64);
        const float pq = __shfl_xor(si[r], 1 << PT, 64);
        sr[r] = c*sr[r] + ss*pr;
        si[r] = c*si[r] + ss*pq;
      }
    } else {
      const bool ctrl = (lane >> PC) & 1;
#pragma unroll
      for (int r = 0; r < 16; ++r) {
        const float pr = __shfl_xor(sr[r], 1 << PT, 64);
        const float pq = __shfl_xor(si[r], 1 << PT, 64);
        const float nr = c*sr[r] + ss*pr;
        const float ni = c*si[r] + ss*pq;
        sr[r] = ctrl ? nr : sr[r];
        si[r] = ctrl ? ni : si[r];
      }
    }
  }
}

} // namespace

__global__ __launch_bounds__(256)
void qlayer_kernel(const float* __restrict__ inp,   // (B, 10)
                   const float* __restrict__ wt,    // (80,)
                   float* __restrict__ out,         // (B, 10)
                   int B)
{
  __shared__ float gm[20][8];   // Rot matrices: layer*10+q -> u00,u01,u10,u11 (re,im)
  __shared__ float gc[20][2];   // CRY: cos(th/2), sin(th/2)

  const int tid = threadIdx.x;
  if (tid < 20) {
    // Rot(phi, theta, omega) = RZ(omega) RY(theta) RZ(phi)
    //  = [ c e^{-i a},  -s e^{i b} ]   a = (phi+omega)/2
    //    [ s e^{-i b},   c e^{i a} ]   b = (phi-omega)/2
    const int layer = tid / 10, q = tid % 10;
    const int w = layer * 40 + 3 * q;
    const float phi = wt[w], th = wt[w + 1], om = wt[w + 2];
    float s, c, sa, ca, sb, cb;
    __sincosf(0.5f * th, &s, &c);
    __sincosf(0.5f * (phi + om), &sa, &ca);
    __sincosf(0.5f * (phi - om), &sb, &cb);
    gm[tid][0] =  c * ca;  gm[tid][1] = -c * sa;   // u00
    gm[tid][2] = -s * cb;  gm[tid][3] = -s * sb;   // u01
    gm[tid][4] =  s * cb;  gm[tid][5] = -s * sb;   // u10
    gm[tid][6] =  c * ca;  gm[tid][7] =  c * sa;   // u11
  } else if (tid < 40) {
    const int g = tid - 20;
    const int layer = g / 10, e = g % 10;
    const int w = layer * 40 + 30 + e;
    float s, c;
    __sincosf(0.5f * wt[w], &s, &c);
    gc[g][0] = c;
    gc[g][1] = s;
  }
  __syncthreads();

  const int lane = tid & 63;
  const int sample = (int)((blockIdx.x * (unsigned)blockDim.x + tid) >> 6);
  if (sample >= B) return;

  // Embedding: product state amp[i] = prod_p (bit_p(i) ? sin : cos)(pi/2 * clip(x_{9-p}))
  float fc[10], fs[10];
#pragma unroll
  for (int p = 0; p < 10; ++p) {
    float x = inp[sample * NQB + (9 - p)];
    x = fminf(fmaxf(x, 0.0f), 1.0f);
    __sincosf(1.57079632679489662f * x, &fs[p], &fc[p]);
  }

  float plane = 1.0f;
#pragma unroll
  for (int p = 0; p < 6; ++p)
    plane *= ((lane >> p) & 1) ? fs[p] : fc[p];

  float sr[16], si[16];
#pragma unroll
  for (int r = 0; r < 16; ++r) {
    const float g = ((r & 1) ? fs[6] : fc[6]) * ((r & 2) ? fs[7] : fc[7])
                  * ((r & 4) ? fs[8] : fc[8]) * ((r & 8) ? fs[9] : fc[9]);
    sr[r] = plane * g;
    si[r] = 0.0f;
  }

  // Two layers: 10 Rot (q=0..9 -> P=9..0), then 10 CRY on ring (u,v)=(e,e+1 mod 10)
#pragma unroll
  for (int L = 0; L < 2; ++L) {
    const float* m = &gm[L * 10][0];
    rot_gate<9>(sr, si, m + 0 * 8, lane);
    rot_gate<8>(sr, si, m + 1 * 8, lane);
    rot_gate<7>(sr, si, m + 2 * 8, lane);
    rot_gate<6>(sr, si, m + 3 * 8, lane);
    rot_gate<5>(sr, si, m + 4 * 8, lane);
    rot_gate<4>(sr, si, m + 5 * 8, lane);
    rot_gate<3>(sr, si, m + 6 * 8, lane);
    rot_gate<2>(sr, si, m + 7 * 8, lane);
    rot_gate<1>(sr, si, m + 8 * 8, lane);
    rot_gate<0>(sr, si, m + 9 * 8, lane);
    const float (*cc)[2] = &gc[L * 10];
    cry_gate<9, 8>(sr, si, cc[0][0], cc[0][1], lane);
    cry_gate<8, 7>(sr, si, cc[1][0], cc[1][1], lane);
    cry_gate<7, 6>(sr, si, cc[2][0], cc[2][1], lane);
    cry_gate<6, 5>(sr, si, cc[3][0], cc[3][1], lane);
    cry_gate<5, 4>(sr, si, cc[4][0], cc[4][1], lane);
    cry_gate<4, 3>(sr, si, cc[5][0], cc[5][1], lane);
    cry_gate<3, 2>(sr, si, cc[6][0], cc[6][1], lane);
    cry_gate<2, 1>(sr, si, cc[7][0], cc[7][1], lane);
    cry_gate<1, 0>(sr, si, cc[8][0], cc[8][1], lane);
    cry_gate<0, 9>(sr, si, cc[9][0], cc[9][1], lane);
  }

  // probs and PauliZ expvals. Sign for bit p: +1 if bit==0.
  float prob[16];
#pragma unroll
  for (int r = 0; r < 16; ++r) prob[r] = sr[r] * sr[r] + si[r] * si[r];

  float tot = 0.f, o6 = 0.f, o7 = 0.f, o8 = 0.f, o9 = 0.f;
#pragma unroll
  for (int r = 0; r < 16; ++r) {
    tot += prob[r];
    o6 += (r & 1) ? -prob[r] : prob[r];
    o7 += (r & 2) ? -prob[r] : prob[r];
    o8 += (r & 4) ? -prob[r] : prob[r];
    o9 += (r & 8) ? -prob[r] : prob[r];
  }
  float o0 = (lane & 1)  ? -tot : tot;
  float o1 = (lane & 2)  ? -tot : tot;
  float o2 = (lane & 4)  ? -tot : tot;
  float o3 = (lane & 8)  ? -tot : tot;
  float o4 = (lane & 16) ? -tot : tot;
  float o5 = (lane & 32) ? -tot : tot;

#pragma unroll
  for (int msk = 1; msk < 64; msk <<= 1) {
    o0 += __shfl_xor(o0, msk, 64);
    o1 += __shfl_xor(o1, msk, 64);
    o2 += __shfl_xor(o2, msk, 64);
    o3 += __shfl_xor(o3, msk, 64);
    o4 += __shfl_xor(o4, msk, 64);
    o5 += __shfl_xor(o5, msk, 64);
    o6 += __shfl_xor(o6, msk, 64);
    o7 += __shfl_xor(o7, msk, 64);
    o8 += __shfl_xor(o8, msk, 64);
    o9 += __shfl_xor(o9, msk, 64);
  }

  // out[sample][q] with q = 9 - p  ->  lane l writes o_{9-l}
  if (lane < 10) {
    float v = o9;
    v = (lane == 1) ? o8 : v;
    v = (lane == 2) ? o7 : v;
    v = (lane == 3) ? o6 : v;
    v = (lane == 4) ? o5 : v;
    v = (lane == 5) ? o4 : v;
    v = (lane == 6) ? o3 : v;
    v = (lane == 7) ? o2 : v;
    v = (lane == 8) ? o1 : v;
    v = (lane == 9) ? o0 : v;
    out[sample * NQB + lane] = v;
  }
}

extern "C" void kernel_launch(void* const* d_in, const int* in_sizes, int n_in,
                              void* d_out, int out_size, void* d_ws, size_t ws_size,
                              hipStream_t stream) {
  const float* inp = (const float*)d_in[0];
  const float* wt  = (const float*)d_in[1];
  float* out = (float*)d_out;
  const int B = in_sizes[0] / NQB;            // 32768
  const int waves_per_block = 4;              // 256 threads
  const int nblocks = (B + waves_per_block - 1) / waves_per_block;
  hipLaunchKernelGGL(qlayer_kernel, dim3(nblocks), dim3(256), 0, stream,
                     inp, wt, out, B);
}

// Round 2
// 277.575 us; speedup vs baseline: 1.0184x; 1.0184x over previous
//
#include <hip/hip_runtime.h>

// 10-qubit batched statevector simulator, packed-fp32 version.
// One wave (64 lanes) per sample. Amp index bits: 0..5 = lane bits,
// 6..8 = k-index bits of v2f arrays, 9 = element (x/y) of each v2f.
// Qubit q (PennyLane wire, MSB-first) lives at bit p = 9 - q.
// v2f math is intended to lower to v_pk_{fma,mul,add}_f32 (gfx90a+ packed fp32).

namespace {

constexpr int NQB = 10;

typedef float v2f __attribute__((ext_vector_type(2)));

__device__ __forceinline__ v2f shfl2(v2f v, int m) {
  v2f r;
  r.x = __shfl_xor(v.x, m, 64);
  r.y = __shfl_xor(v.y, m, 64);
  return r;
}

// ---- Rot gates (complex 2x2, wave-uniform matrix m[8] = u00,u01,u10,u11 re/im) ----

// Register-bit gate, J in k-space (1,2,4 <-> amp bits 6,7,8)
template<int J>
__device__ __forceinline__ void rot_reg(v2f (&Sr)[8], v2f (&Si)[8], const float* m) {
  const float u00r=m[0],u00i=m[1],u01r=m[2],u01i=m[3];
  const float u10r=m[4],u10i=m[5],u11r=m[6],u11i=m[7];
#pragma unroll
  for (int k0 = 0; k0 < 8; ++k0) {
    if (k0 & J) continue;
    const int k1 = k0 | J;
    const v2f a0r=Sr[k0], a0i=Si[k0], a1r=Sr[k1], a1i=Si[k1];
    Sr[k0] = u00r*a0r - u00i*a0i + u01r*a1r - u01i*a1i;
    Si[k0] = u00r*a0i + u00i*a0r + u01r*a1i + u01i*a1r;
    Sr[k1] = u10r*a0r - u10i*a0i + u11r*a1r - u11i*a1i;
    Si[k1] = u10r*a0i + u10i*a0r + u11r*a1i + u11i*a1r;
  }
}

// Packing-axis gate (amp bit 9 = element index of the v2f)
__device__ __forceinline__ void rot_axis(v2f (&Sr)[8], v2f (&Si)[8], const float* m) {
  const v2f U0r = {m[0], m[4]}, U0i = {m[1], m[5]};
  const v2f U1r = {m[2], m[6]}, U1i = {m[3], m[7]};
#pragma unroll
  for (int k = 0; k < 8; ++k) {
    const v2f ar = Sr[k], ai = Si[k];
    Sr[k] = U0r*ar.xx - U0i*ai.xx + U1r*ar.yy - U1i*ai.yy;
    Si[k] = U0r*ai.xx + U0i*ar.xx + U1r*ai.yy + U1i*ar.yy;
  }
}

// Lane-bit gate (amp bit P < 6)
template<int P>
__device__ __forceinline__ void rot_lane(v2f (&Sr)[8], v2f (&Si)[8], const float* m, int lane) {
  const int bit = (lane >> P) & 1;
  const float uar = bit ? m[6] : m[0];
  const float uai = bit ? m[7] : m[1];
  const float ubr = bit ? m[4] : m[2];
  const float ubi = bit ? m[5] : m[3];
#pragma unroll
  for (int k = 0; k < 8; ++k) {
    const v2f ar = Sr[k], ai = Si[k];
    const v2f pr = shfl2(ar, 1 << P), pi = shfl2(ai, 1 << P);
    Sr[k] = uar*ar - uai*ai + ubr*pr - ubi*pi;
    Si[k] = uar*ai + uai*ar + ubr*pi + ubi*pr;
  }
}

// ---- CRY gates (real c = cos(th/2), s = sin(th/2); control==1 applies RY) ----

// control & target both register k-bits
template<int CB, int J>
__device__ __forceinline__ void cry_reg_reg(v2f (&Sr)[8], v2f (&Si)[8], float c, float s) {
#pragma unroll
  for (int k0 = 0; k0 < 8; ++k0) {
    if ((k0 & J) || !(k0 & CB)) continue;
    const int k1 = k0 | J;
    const v2f a0r=Sr[k0], a0i=Si[k0], a1r=Sr[k1], a1i=Si[k1];
    Sr[k0] = c*a0r - s*a1r;  Si[k0] = c*a0i - s*a1i;
    Sr[k1] = s*a0r + c*a1r;  Si[k1] = s*a0i + c*a1i;
  }
}

// control on packing axis (bit 9), target k-bit 4 (amp bit 8): fold control into coeff vectors
__device__ __forceinline__ void cry_axisctrl(v2f (&Sr)[8], v2f (&Si)[8], float c, float s) {
  const v2f cv = {1.0f, c}, sv = {0.0f, s};
#pragma unroll
  for (int k0 = 0; k0 < 4; ++k0) {
    const int k1 = k0 + 4;
    const v2f a0r=Sr[k0], a0i=Si[k0], a1r=Sr[k1], a1i=Si[k1];
    Sr[k0] = cv*a0r - sv*a1r;  Si[k0] = cv*a0i - sv*a1i;
    Sr[k1] = sv*a0r + cv*a1r;  Si[k1] = sv*a0i + cv*a1i;
  }
}

// control k-bit 1 (amp bit 6), target lane bit 5
__device__ __forceinline__ void cry_k0ctrl_lane5(v2f (&Sr)[8], v2f (&Si)[8], float c, float s, int lane) {
  const float ss = ((lane >> 5) & 1) ? s : -s;
#pragma unroll
  for (int k = 1; k < 8; k += 2) {
    const v2f pr = shfl2(Sr[k], 32), pi = shfl2(Si[k], 32);
    Sr[k] = c*Sr[k] + ss*pr;
    Si[k] = c*Si[k] + ss*pi;
  }
}

// control & target both lane bits: fold control into per-lane coefficients
template<int PC, int PT>
__device__ __forceinline__ void cry_lane_lane(v2f (&Sr)[8], v2f (&Si)[8], float c, float s, int lane) {
  const bool ctrl = (lane >> PC) & 1;
  const float ce = ctrl ? c : 1.0f;
  const float se = ctrl ? s : 0.0f;
  const float ss = ((lane >> PT) & 1) ? se : -se;
#pragma unroll
  for (int k = 0; k < 8; ++k) {
    const v2f pr = shfl2(Sr[k], 1 << PT), pi = shfl2(Si[k], 1 << PT);
    Sr[k] = ce*Sr[k] + ss*pr;
    Si[k] = ce*Si[k] + ss*pi;
  }
}

// control lane bit 0, target packing axis (bit 9): intra-v2f rotation via .yx swizzle
__device__ __forceinline__ void cry_lanectrl_axis(v2f (&Sr)[8], v2f (&Si)[8], float c, float s, int lane) {
  const bool ctrl = lane & 1;
  const float ce = ctrl ? c : 1.0f;
  const float se = ctrl ? s : 0.0f;
  const v2f sv = {-se, se};
#pragma unroll
  for (int k = 0; k < 8; ++k) {
    const v2f ar = Sr[k], ai = Si[k];
    Sr[k] = ce*ar + sv*ar.yx;
    Si[k] = ce*ai + sv*ai.yx;
  }
}

} // namespace

__global__ __launch_bounds__(256)
void qlayer_kernel(const float* __restrict__ inp,   // (B, 10)
                   const float* __restrict__ wt,    // (80,)
                   float* __restrict__ out,         // (B, 10)
                   int B)
{
  __shared__ float gm[20][8];   // Rot matrices: layer*10+q -> u00,u01,u10,u11 (re,im)
  __shared__ float gc[20][2];   // CRY: cos(th/2), sin(th/2)

  const int tid = threadIdx.x;
  if (tid < 20) {
    // Rot(phi, theta, omega) = RZ(omega) RY(theta) RZ(phi)
    //  = [ c e^{-i a},  -s e^{i b} ]   a = (phi+omega)/2
    //    [ s e^{-i b},   c e^{i a} ]   b = (phi-omega)/2
    const int layer = tid / 10, q = tid % 10;
    const int w = layer * 40 + 3 * q;
    const float phi = wt[w], th = wt[w + 1], om = wt[w + 2];
    float s, c, sa, ca, sb, cb;
    __sincosf(0.5f * th, &s, &c);
    __sincosf(0.5f * (phi + om), &sa, &ca);
    __sincosf(0.5f * (phi - om), &sb, &cb);
    gm[tid][0] =  c * ca;  gm[tid][1] = -c * sa;   // u00
    gm[tid][2] = -s * cb;  gm[tid][3] = -s * sb;   // u01
    gm[tid][4] =  s * cb;  gm[tid][5] = -s * sb;   // u10
    gm[tid][6] =  c * ca;  gm[tid][7] =  c * sa;   // u11
  } else if (tid < 40) {
    const int g = tid - 20;
    const int layer = g / 10, e = g % 10;
    const int w = layer * 40 + 30 + e;
    float s, c;
    __sincosf(0.5f * wt[w], &s, &c);
    gc[g][0] = c;
    gc[g][1] = s;
  }
  __syncthreads();

  const int lane = tid & 63;
  const int sample = (int)((blockIdx.x * (unsigned)blockDim.x + tid) >> 6);
  if (sample >= B) return;

  // Embedding: product state amp[i] = prod_p (bit_p(i) ? sin : cos)(pi/2 * clip(x_{9-p}))
  float fc[10], fs[10];
#pragma unroll
  for (int p = 0; p < 10; ++p) {
    float x = inp[sample * NQB + (9 - p)];
    x = fminf(fmaxf(x, 0.0f), 1.0f);
    __sincosf(1.57079632679489662f * x, &fs[p], &fc[p]);
  }

  float plane = 1.0f;
#pragma unroll
  for (int p = 0; p < 6; ++p)
    plane *= ((lane >> p) & 1) ? fs[p] : fc[p];

  v2f Sr[8], Si[8];
#pragma unroll
  for (int k = 0; k < 8; ++k) {
    const float gk = ((k & 1) ? fs[6] : fc[6]) * ((k & 2) ? fs[7] : fc[7])
                   * ((k & 4) ? fs[8] : fc[8]);
    v2f v; v.x = plane * gk * fc[9]; v.y = plane * gk * fs[9];
    Sr[k] = v;
    Si[k] = (v2f){0.0f, 0.0f};
  }

  // Two layers: 10 Rot (q=0..9 -> amp bit P=9..0), then ring CRYs (u,v)=(e, e+1 mod 10)
#pragma unroll
  for (int L = 0; L < 2; ++L) {
    const float* m = &gm[L * 10][0];
    rot_axis      (Sr, Si, m + 0 * 8);        // q=0, P=9
    rot_reg<4>    (Sr, Si, m + 1 * 8);        // q=1, P=8
    rot_reg<2>    (Sr, Si, m + 2 * 8);        // q=2, P=7
    rot_reg<1>    (Sr, Si, m + 3 * 8);        // q=3, P=6
    rot_lane<5>   (Sr, Si, m + 4 * 8, lane);
    rot_lane<4>   (Sr, Si, m + 5 * 8, lane);
    rot_lane<3>   (Sr, Si, m + 6 * 8, lane);
    rot_lane<2>   (Sr, Si, m + 7 * 8, lane);
    rot_lane<1>   (Sr, Si, m + 8 * 8, lane);
    rot_lane<0>   (Sr, Si, m + 9 * 8, lane);
    const float (*cc)[2] = &gc[L * 10];
    cry_axisctrl        (Sr, Si, cc[0][0], cc[0][1]);        // (ctrl P=9, tgt P=8)
    cry_reg_reg<4, 2>   (Sr, Si, cc[1][0], cc[1][1]);        // (8,7)
    cry_reg_reg<2, 1>   (Sr, Si, cc[2][0], cc[2][1]);        // (7,6)
    cry_k0ctrl_lane5    (Sr, Si, cc[3][0], cc[3][1], lane);  // (6,5)
    cry_lane_lane<5, 4> (Sr, Si, cc[4][0], cc[4][1], lane);
    cry_lane_lane<4, 3> (Sr, Si, cc[5][0], cc[5][1], lane);
    cry_lane_lane<3, 2> (Sr, Si, cc[6][0], cc[6][1], lane);
    cry_lane_lane<2, 1> (Sr, Si, cc[7][0], cc[7][1], lane);
    cry_lane_lane<1, 0> (Sr, Si, cc[8][0], cc[8][1], lane);
    cry_lanectrl_axis   (Sr, Si, cc[9][0], cc[9][1], lane);  // (0,9)
  }

  // ---- probabilities and PauliZ expvals ----
  v2f P[8];
#pragma unroll
  for (int k = 0; k < 8; ++k) P[k] = Sr[k]*Sr[k] + Si[k]*Si[k];

  // register-bit contractions (packed)
  const v2f q01 = P[0]+P[1], q23 = P[2]+P[3], q45 = P[4]+P[5], q67 = P[6]+P[7];
  const v2f h1 = q01+q23, h2 = q45+q67;
  const v2f t2 = h1 + h2;                           // per-lane total (x: bit9=0, y: bit9=1)
  const v2f e8v = h1 - h2;                          // sign on amp bit 8
  const v2f e7v = (q01 - q23) + (q45 - q67);        // sign on amp bit 7
  const v2f d01 = P[0]-P[1], d23 = P[2]-P[3], d45 = P[4]-P[5], d67 = P[6]-P[7];
  const v2f e6v = (d01 + d23) + (d45 + d67);        // sign on amp bit 6

  const float tot = t2.x + t2.y;
  float o6 = e6v.x + e6v.y;
  float o7 = e7v.x + e7v.y;
  float o8 = e8v.x + e8v.y;
  float o9 = t2.x - t2.y;

  // lane-bit signed reductions: spawn difference streams during the sum butterfly
  float sgn[6];
#pragma unroll
  for (int p = 0; p < 6; ++p) sgn[p] = ((lane >> p) & 1) ? -1.0f : 1.0f;

  float t = tot;
  float E[6];
#pragma unroll
  for (int p = 0; p < 6; ++p) {
    const int m = 1 << p;
    const float pt = __shfl_xor(t, m, 64);
    E[p] = sgn[p] * (t - pt);
    t += pt;
#pragma unroll
    for (int j = 0; j < p; ++j)
      E[j] += __shfl_xor(E[j], m, 64);
  }

  // plain reductions of the register-bit expvals (packed, 2 streams)
  v2f q1; q1.x = o6; q1.y = o7;
  v2f q2; q2.x = o8; q2.y = o9;
#pragma unroll
  for (int m = 1; m < 64; m <<= 1) {
    q1 += shfl2(q1, m);
    q2 += shfl2(q2, m);
  }

  // out[sample][q], q = 9 - p:  q=0..3 <- R9,R8,R7,R6 ; q=4..9 <- E[5..0]
  if (lane < 10) {
    float v = q2.y;                  // q=0: bit 9
    v = (lane == 1) ? q2.x : v;      // bit 8
    v = (lane == 2) ? q1.y : v;      // bit 7
    v = (lane == 3) ? q1.x : v;      // bit 6
    v = (lane == 4) ? E[5] : v;
    v = (lane == 5) ? E[4] : v;
    v = (lane == 6) ? E[3] : v;
    v = (lane == 7) ? E[2] : v;
    v = (lane == 8) ? E[1] : v;
    v = (lane == 9) ? E[0] : v;
    out[sample * NQB + lane] = v;
  }
}

extern "C" void kernel_launch(void* const* d_in, const int* in_sizes, int n_in,
                              void* d_out, int out_size, void* d_ws, size_t ws_size,
                              hipStream_t stream) {
  const float* inp = (const float*)d_in[0];
  const float* wt  = (const float*)d_in[1];
  float* out = (float*)d_out;
  const int B = in_sizes[0] / NQB;            // 32768
  const int waves_per_block = 4;              // 256 threads
  const int nblocks = (B + waves_per_block - 1) / waves_per_block;
  hipLaunchKernelGGL(qlayer_kernel, dim3(nblocks), dim3(256), 0, stream,
                     inp, wt, out, B);
}

// Round 4
// 219.444 us; speedup vs baseline: 1.2882x; 1.2649x over previous
//
#include <hip/hip_runtime.h>

// 10-qubit batched statevector simulator, packed-fp32 + VALU-cross-lane version.
// One wave (64 lanes) per sample. Amp index bits: 0..5 = lane bits,
// 6..8 = k-index bits of v2f arrays, 9 = element (x/y) of each v2f.
// Qubit q (PennyLane wire, MSB-first) lives at bit p = 9 - q.
// All lane-XOR exchange is on the VALU pipe (DPP quad_perm / row_ror:8 /
// half-mirror compositions, gfx950 v_permlane16/32_swap_b32) -- round-2
// profile showed the DS pipe (ds_bpermute) saturated while VALU sat at 40%.
//
// permlane swap semantics (CDNA4 ISA): swap(x,x) ->
//   permlane16: r.x[lane] = x[lane & ~16], r.y[lane] = x[lane | 16]
//   permlane32: r.x[lane] = x[lane & ~32], r.y[lane] = x[lane | 32]
// so partner(x, lane^bit) = bit_set(lane) ? r.x : r.y.   (round-3 bug: inverted)

namespace {

constexpr int NQB = 10;

typedef float v2f __attribute__((ext_vector_type(2)));
typedef unsigned int u32x2 __attribute__((ext_vector_type(2)));

template<int CTRL>
__device__ __forceinline__ float dppf(float x) {
  return __uint_as_float((unsigned)__builtin_amdgcn_update_dpp(
      0, (int)__float_as_uint(x), CTRL, 0xF, 0xF, true));
}

// Partner value x[lane ^ (1<<P)] via VALU-only cross-lane ops.
template<int P>
__device__ __forceinline__ float xorf(float x, int lane) {
  if constexpr (P == 0) {
    return dppf<0xB1>(x);                       // quad_perm [1,0,3,2] = XOR1
  } else if constexpr (P == 1) {
    return dppf<0x4E>(x);                       // quad_perm [2,3,0,1] = XOR2
  } else if constexpr (P == 2) {
    return dppf<0x141>(dppf<0x1B>(x));          // XOR3 then XOR7 => XOR4
  } else if constexpr (P == 3) {
    return dppf<0x128>(x);                      // row_ror:8 == XOR8 within row16
  } else if constexpr (P == 4) {
#if __has_builtin(__builtin_amdgcn_permlane16_swap)
    u32x2 r = __builtin_amdgcn_permlane16_swap(__float_as_uint(x), __float_as_uint(x), false, false);
    // r.x[lane] = x[lane & ~16]; r.y[lane] = x[lane | 16]
    return __uint_as_float(((lane >> 4) & 1) ? r.x : r.y);
#else
    return __shfl_xor(x, 16, 64);
#endif
  } else {
#if __has_builtin(__builtin_amdgcn_permlane32_swap)
    u32x2 r = __builtin_amdgcn_permlane32_swap(__float_as_uint(x), __float_as_uint(x), false, false);
    // r.x[lane] = x[lane & ~32]; r.y[lane] = x[lane | 32]
    return __uint_as_float((lane >= 32) ? r.x : r.y);
#else
    return __shfl_xor(x, 32, 64);
#endif
  }
}

template<int P>
__device__ __forceinline__ v2f partner2(v2f v, int lane) {
  v2f r;
  r.x = xorf<P>(v.x, lane);
  r.y = xorf<P>(v.y, lane);
  return r;
}

// ---- Rot gates (complex 2x2, wave-uniform matrix m[8] = u00,u01,u10,u11 re/im) ----

// Register-bit gate, J in k-space (1,2,4 <-> amp bits 6,7,8)
template<int J>
__device__ __forceinline__ void rot_reg(v2f (&Sr)[8], v2f (&Si)[8], const float* m) {
  const float u00r=m[0],u00i=m[1],u01r=m[2],u01i=m[3];
  const float u10r=m[4],u10i=m[5],u11r=m[6],u11i=m[7];
#pragma unroll
  for (int k0 = 0; k0 < 8; ++k0) {
    if (k0 & J) continue;
    const int k1 = k0 | J;
    const v2f a0r=Sr[k0], a0i=Si[k0], a1r=Sr[k1], a1i=Si[k1];
    Sr[k0] = u00r*a0r - u00i*a0i + u01r*a1r - u01i*a1i;
    Si[k0] = u00r*a0i + u00i*a0r + u01r*a1i + u01i*a1r;
    Sr[k1] = u10r*a0r - u10i*a0i + u11r*a1r - u11i*a1i;
    Si[k1] = u10r*a0i + u10i*a0r + u11r*a1i + u11i*a1r;
  }
}

// Packing-axis gate (amp bit 9 = element index of the v2f)
__device__ __forceinline__ void rot_axis(v2f (&Sr)[8], v2f (&Si)[8], const float* m) {
  const v2f U0r = {m[0], m[4]}, U0i = {m[1], m[5]};
  const v2f U1r = {m[2], m[6]}, U1i = {m[3], m[7]};
#pragma unroll
  for (int k = 0; k < 8; ++k) {
    const v2f ar = Sr[k], ai = Si[k];
    Sr[k] = U0r*ar.xx - U0i*ai.xx + U1r*ar.yy - U1i*ai.yy;
    Si[k] = U0r*ai.xx + U0i*ar.xx + U1r*ai.yy + U1i*ar.yy;
  }
}

// Lane-bit gate (amp bit P < 6)
template<int P>
__device__ __forceinline__ void rot_lane(v2f (&Sr)[8], v2f (&Si)[8], const float* m, int lane) {
  const int bit = (lane >> P) & 1;
  const float uar = bit ? m[6] : m[0];
  const float uai = bit ? m[7] : m[1];
  const float ubr = bit ? m[4] : m[2];
  const float ubi = bit ? m[5] : m[3];
#pragma unroll
  for (int k = 0; k < 8; ++k) {
    const v2f ar = Sr[k], ai = Si[k];
    const v2f pr = partner2<P>(ar, lane), pi = partner2<P>(ai, lane);
    Sr[k] = uar*ar - uai*ai + ubr*pr - ubi*pi;
    Si[k] = uar*ai + uai*ar + ubr*pi + ubi*pr;
  }
}

// ---- CRY gates (real c = cos(th/2), s = sin(th/2); control==1 applies RY) ----

// control & target both register k-bits
template<int CB, int J>
__device__ __forceinline__ void cry_reg_reg(v2f (&Sr)[8], v2f (&Si)[8], float c, float s) {
#pragma unroll
  for (int k0 = 0; k0 < 8; ++k0) {
    if ((k0 & J) || !(k0 & CB)) continue;
    const int k1 = k0 | J;
    const v2f a0r=Sr[k0], a0i=Si[k0], a1r=Sr[k1], a1i=Si[k1];
    Sr[k0] = c*a0r - s*a1r;  Si[k0] = c*a0i - s*a1i;
    Sr[k1] = s*a0r + c*a1r;  Si[k1] = s*a0i + c*a1i;
  }
}

// control on packing axis (bit 9), target k-bit 4 (amp bit 8): fold control into coeff vectors
__device__ __forceinline__ void cry_axisctrl(v2f (&Sr)[8], v2f (&Si)[8], float c, float s) {
  const v2f cv = {1.0f, c}, sv = {0.0f, s};
#pragma unroll
  for (int k0 = 0; k0 < 4; ++k0) {
    const int k1 = k0 + 4;
    const v2f a0r=Sr[k0], a0i=Si[k0], a1r=Sr[k1], a1i=Si[k1];
    Sr[k0] = cv*a0r - sv*a1r;  Si[k0] = cv*a0i - sv*a1i;
    Sr[k1] = sv*a0r + cv*a1r;  Si[k1] = sv*a0i + cv*a1i;
  }
}

// control k-bit 1 (amp bit 6), target lane bit 5
__device__ __forceinline__ void cry_k0ctrl_lane5(v2f (&Sr)[8], v2f (&Si)[8], float c, float s, int lane) {
  const float ss = ((lane >> 5) & 1) ? s : -s;
#pragma unroll
  for (int k = 1; k < 8; k += 2) {
    const v2f pr = partner2<5>(Sr[k], lane), pi = partner2<5>(Si[k], lane);
    Sr[k] = c*Sr[k] + ss*pr;
    Si[k] = c*Si[k] + ss*pi;
  }
}

// control & target both lane bits: fold control into per-lane coefficients
template<int PC, int PT>
__device__ __forceinline__ void cry_lane_lane(v2f (&Sr)[8], v2f (&Si)[8], float c, float s, int lane) {
  const bool ctrl = (lane >> PC) & 1;
  const float ce = ctrl ? c : 1.0f;
  const float se = ctrl ? s : 0.0f;
  const float ss = ((lane >> PT) & 1) ? se : -se;
#pragma unroll
  for (int k = 0; k < 8; ++k) {
    const v2f pr = partner2<PT>(Sr[k], lane), pi = partner2<PT>(Si[k], lane);
    Sr[k] = ce*Sr[k] + ss*pr;
    Si[k] = ce*Si[k] + ss*pi;
  }
}

// control lane bit 0, target packing axis (bit 9): intra-v2f rotation via .yx swizzle
__device__ __forceinline__ void cry_lanectrl_axis(v2f (&Sr)[8], v2f (&Si)[8], float c, float s, int lane) {
  const bool ctrl = lane & 1;
  const float ce = ctrl ? c : 1.0f;
  const float se = ctrl ? s : 0.0f;
  const v2f sv = {-se, se};
#pragma unroll
  for (int k = 0; k < 8; ++k) {
    const v2f ar = Sr[k], ai = Si[k];
    Sr[k] = ce*ar + sv*ar.yx;
    Si[k] = ce*ai + sv*ai.yx;
  }
}

} // namespace

__global__ __launch_bounds__(256)
void qlayer_kernel(const float* __restrict__ inp,   // (B, 10)
                   const float* __restrict__ wt,    // (80,)
                   float* __restrict__ out,         // (B, 10)
                   int B)
{
  __shared__ float gm[20][8];   // Rot matrices: layer*10+q -> u00,u01,u10,u11 (re,im)
  __shared__ float gc[20][2];   // CRY: cos(th/2), sin(th/2)

  const int tid = threadIdx.x;
  if (tid < 20) {
    // Rot(phi, theta, omega) = RZ(omega) RY(theta) RZ(phi)
    //  = [ c e^{-i a},  -s e^{i b} ]   a = (phi+omega)/2
    //    [ s e^{-i b},   c e^{i a} ]   b = (phi-omega)/2
    const int layer = tid / 10, q = tid % 10;
    const int w = layer * 40 + 3 * q;
    const float phi = wt[w], th = wt[w + 1], om = wt[w + 2];
    float s, c, sa, ca, sb, cb;
    __sincosf(0.5f * th, &s, &c);
    __sincosf(0.5f * (phi + om), &sa, &ca);
    __sincosf(0.5f * (phi - om), &sb, &cb);
    gm[tid][0] =  c * ca;  gm[tid][1] = -c * sa;   // u00
    gm[tid][2] = -s * cb;  gm[tid][3] = -s * sb;   // u01
    gm[tid][4] =  s * cb;  gm[tid][5] = -s * sb;   // u10
    gm[tid][6] =  c * ca;  gm[tid][7] =  c * sa;   // u11
  } else if (tid < 40) {
    const int g = tid - 20;
    const int layer = g / 10, e = g % 10;
    const int w = layer * 40 + 30 + e;
    float s, c;
    __sincosf(0.5f * wt[w], &s, &c);
    gc[g][0] = c;
    gc[g][1] = s;
  }
  __syncthreads();

  const int lane = tid & 63;
  const int sample = (int)((blockIdx.x * (unsigned)blockDim.x + tid) >> 6);
  if (sample >= B) return;

  // Embedding: product state amp[i] = prod_p (bit_p(i) ? sin : cos)(pi/2 * clip(x_{9-p}))
  float fc[10], fs[10];
#pragma unroll
  for (int p = 0; p < 10; ++p) {
    float x = inp[sample * NQB + (9 - p)];
    x = fminf(fmaxf(x, 0.0f), 1.0f);
    __sincosf(1.57079632679489662f * x, &fs[p], &fc[p]);
  }

  float plane = 1.0f;
#pragma unroll
  for (int p = 0; p < 6; ++p)
    plane *= ((lane >> p) & 1) ? fs[p] : fc[p];

  v2f Sr[8], Si[8];
#pragma unroll
  for (int k = 0; k < 8; ++k) {
    const float gk = ((k & 1) ? fs[6] : fc[6]) * ((k & 2) ? fs[7] : fc[7])
                   * ((k & 4) ? fs[8] : fc[8]);
    v2f v; v.x = plane * gk * fc[9]; v.y = plane * gk * fs[9];
    Sr[k] = v;
    Si[k] = (v2f){0.0f, 0.0f};
  }

  // Two layers: 10 Rot (q=0..9 -> amp bit P=9..0), then ring CRYs (u,v)=(e, e+1 mod 10)
#pragma unroll
  for (int L = 0; L < 2; ++L) {
    const float* m = &gm[L * 10][0];
    rot_axis      (Sr, Si, m + 0 * 8);        // q=0, P=9
    rot_reg<4>    (Sr, Si, m + 1 * 8);        // q=1, P=8
    rot_reg<2>    (Sr, Si, m + 2 * 8);        // q=2, P=7
    rot_reg<1>    (Sr, Si, m + 3 * 8);        // q=3, P=6
    rot_lane<5>   (Sr, Si, m + 4 * 8, lane);
    rot_lane<4>   (Sr, Si, m + 5 * 8, lane);
    rot_lane<3>   (Sr, Si, m + 6 * 8, lane);
    rot_lane<2>   (Sr, Si, m + 7 * 8, lane);
    rot_lane<1>   (Sr, Si, m + 8 * 8, lane);
    rot_lane<0>   (Sr, Si, m + 9 * 8, lane);
    const float (*cc)[2] = &gc[L * 10];
    cry_axisctrl        (Sr, Si, cc[0][0], cc[0][1]);        // (ctrl P=9, tgt P=8)
    cry_reg_reg<4, 2>   (Sr, Si, cc[1][0], cc[1][1]);        // (8,7)
    cry_reg_reg<2, 1>   (Sr, Si, cc[2][0], cc[2][1]);        // (7,6)
    cry_k0ctrl_lane5    (Sr, Si, cc[3][0], cc[3][1], lane);  // (6,5)
    cry_lane_lane<5, 4> (Sr, Si, cc[4][0], cc[4][1], lane);
    cry_lane_lane<4, 3> (Sr, Si, cc[5][0], cc[5][1], lane);
    cry_lane_lane<3, 2> (Sr, Si, cc[6][0], cc[6][1], lane);
    cry_lane_lane<2, 1> (Sr, Si, cc[7][0], cc[7][1], lane);
    cry_lane_lane<1, 0> (Sr, Si, cc[8][0], cc[8][1], lane);
    cry_lanectrl_axis   (Sr, Si, cc[9][0], cc[9][1], lane);  // (0,9)
  }

  // ---- probabilities and PauliZ expvals ----
  v2f P[8];
#pragma unroll
  for (int k = 0; k < 8; ++k) P[k] = Sr[k]*Sr[k] + Si[k]*Si[k];

  // register-bit contractions (packed)
  const v2f q01 = P[0]+P[1], q23 = P[2]+P[3], q45 = P[4]+P[5], q67 = P[6]+P[7];
  const v2f h1 = q01+q23, h2 = q45+q67;
  const v2f t2 = h1 + h2;                           // per-lane total (x: bit9=0, y: bit9=1)
  const v2f e8v = h1 - h2;                          // sign on amp bit 8
  const v2f e7v = (q01 - q23) + (q45 - q67);        // sign on amp bit 7
  const v2f d01 = P[0]-P[1], d23 = P[2]-P[3], d45 = P[4]-P[5], d67 = P[6]-P[7];
  const v2f e6v = (d01 + d23) + (d45 + d67);        // sign on amp bit 6

  const float tot = t2.x + t2.y;
  const float o6 = e6v.x + e6v.y;
  const float o7 = e7v.x + e7v.y;
  const float o8 = e8v.x + e8v.y;
  const float o9 = t2.x - t2.y;

  // lane-bit signed reductions: spawn difference streams during the sum butterfly
  float sgn[6];
#pragma unroll
  for (int p = 0; p < 6; ++p) sgn[p] = ((lane >> p) & 1) ? -1.0f : 1.0f;

  float E[6];
  float t = tot;
#define QSTEP(P)                                              \
  {                                                           \
    const float pt = xorf<P>(t, lane);                        \
    E[P] = sgn[P] * (t - pt);                                 \
    t += pt;                                                  \
    _Pragma("unroll")                                         \
    for (int j = 0; j < P; ++j) E[j] += xorf<P>(E[j], lane);  \
  }
  QSTEP(0) QSTEP(1) QSTEP(2) QSTEP(3) QSTEP(4) QSTEP(5)
#undef QSTEP

  // plain reductions of the register-bit expvals (packed, 2 streams)
  v2f q1; q1.x = o6; q1.y = o7;
  v2f q2; q2.x = o8; q2.y = o9;
#define RSTEP(P)                    \
  q1 += partner2<P>(q1, lane);      \
  q2 += partner2<P>(q2, lane);
  RSTEP(0) RSTEP(1) RSTEP(2) RSTEP(3) RSTEP(4) RSTEP(5)
#undef RSTEP

  // out[sample][q], q = 9 - p:  q=0..3 <- bits 9,8,7,6 ; q=4..9 <- E[5..0]
  if (lane < 10) {
    float v = q2.y;                  // q=0: bit 9
    v = (lane == 1) ? q2.x : v;      // bit 8
    v = (lane == 2) ? q1.y : v;      // bit 7
    v = (lane == 3) ? q1.x : v;      // bit 6
    v = (lane == 4) ? E[5] : v;
    v = (lane == 5) ? E[4] : v;
    v = (lane == 6) ? E[3] : v;
    v = (lane == 7) ? E[2] : v;
    v = (lane == 8) ? E[1] : v;
    v = (lane == 9) ? E[0] : v;
    out[sample * NQB + lane] = v;
  }
}

extern "C" void kernel_launch(void* const* d_in, const int* in_sizes, int n_in,
                              void* d_out, int out_size, void* d_ws, size_t ws_size,
                              hipStream_t stream) {
  const float* inp = (const float*)d_in[0];
  const float* wt  = (const float*)d_in[1];
  float* out = (float*)d_out;
  const int B = in_sizes[0] / NQB;            // 32768
  const int waves_per_block = 4;              // 256 threads
  const int nblocks = (B + waves_per_block - 1) / waves_per_block;
  hipLaunchKernelGGL(qlayer_kernel, dim3(nblocks), dim3(256), 0, stream,
                     inp, wt, out, B);
}

// Round 5
// 138.457 us; speedup vs baseline: 2.0418x; 1.5849x over previous
//
#include <hip/hip_runtime.h>

// 10-qubit batched statevector simulator.
// One wave (64 lanes) per sample. Amp index bits: 0..5 = lane bits,
// 6..8 = k-index bits of v2f arrays, 9 = element (x/y) of each v2f.
// Qubit q (PennyLane wire, MSB-first) lives at amp bit p = 9 - q.
//
// Round-5 changes vs round-4 (VALU-issue-bound at 94% busy):
//  (a) layer-0 Rot folded into the initial product state (still a product
//      state: per-qubit u_q = Rot_q * (cos,sin)^T) -- removes 10 gates.
//  (b) bit-4/bit-5 partner exchange moved to the idle DS pipe
//      (ds_swizzle XOR16 / ds_bpermute XOR32), balancing VALU vs DS.
// Cross-lane bits 0..3 stay on VALU DPP (1-2 instr each, verified round 4).

namespace {

constexpr int NQB = 10;

typedef float v2f __attribute__((ext_vector_type(2)));

template<int CTRL>
__device__ __forceinline__ float dppf(float x) {
  return __uint_as_float((unsigned)__builtin_amdgcn_update_dpp(
      0, (int)__float_as_uint(x), CTRL, 0xF, 0xF, true));
}

// Partner value x[lane ^ (1<<P)].
// P=0..3: VALU DPP. P=4: DS swizzle (XOR16). P=5: DS bpermute (XOR32, addr bpa).
template<int P>
__device__ __forceinline__ float xorf(float x, int bpa) {
  if constexpr (P == 0) {
    return dppf<0xB1>(x);                       // quad_perm [1,0,3,2] = XOR1
  } else if constexpr (P == 1) {
    return dppf<0x4E>(x);                       // quad_perm [2,3,0,1] = XOR2
  } else if constexpr (P == 2) {
    return dppf<0x141>(dppf<0x1B>(x));          // XOR3 then XOR7 => XOR4
  } else if constexpr (P == 3) {
    return dppf<0x128>(x);                      // row_ror:8 == XOR8 within row16
  } else if constexpr (P == 4) {
    return __uint_as_float((unsigned)__builtin_amdgcn_ds_swizzle(
        (int)__float_as_uint(x), 0x401F));      // bitmode xor=16, and=0x1F
  } else {
    return __uint_as_float((unsigned)__builtin_amdgcn_ds_bpermute(
        bpa, (int)__float_as_uint(x)));         // bpa = (lane^32)<<2
  }
}

template<int P>
__device__ __forceinline__ v2f partner2(v2f v, int bpa) {
  v2f r;
  r.x = xorf<P>(v.x, bpa);
  r.y = xorf<P>(v.y, bpa);
  return r;
}

__device__ __forceinline__ void cmul(float& r, float& i, float br, float bi) {
  const float tr = r * br - i * bi;
  i = r * bi + i * br;
  r = tr;
}

// ---- Rot gates (complex 2x2, wave-uniform matrix m[8] = u00,u01,u10,u11 re/im) ----

template<int J>
__device__ __forceinline__ void rot_reg(v2f (&Sr)[8], v2f (&Si)[8], const float* m) {
  const float u00r=m[0],u00i=m[1],u01r=m[2],u01i=m[3];
  const float u10r=m[4],u10i=m[5],u11r=m[6],u11i=m[7];
#pragma unroll
  for (int k0 = 0; k0 < 8; ++k0) {
    if (k0 & J) continue;
    const int k1 = k0 | J;
    const v2f a0r=Sr[k0], a0i=Si[k0], a1r=Sr[k1], a1i=Si[k1];
    Sr[k0] = u00r*a0r - u00i*a0i + u01r*a1r - u01i*a1i;
    Si[k0] = u00r*a0i + u00i*a0r + u01r*a1i + u01i*a1r;
    Sr[k1] = u10r*a0r - u10i*a0i + u11r*a1r - u11i*a1i;
    Si[k1] = u10r*a0i + u10i*a0r + u11r*a1i + u11i*a1r;
  }
}

__device__ __forceinline__ void rot_axis(v2f (&Sr)[8], v2f (&Si)[8], const float* m) {
  const v2f U0r = {m[0], m[4]}, U0i = {m[1], m[5]};
  const v2f U1r = {m[2], m[6]}, U1i = {m[3], m[7]};
#pragma unroll
  for (int k = 0; k < 8; ++k) {
    const v2f ar = Sr[k], ai = Si[k];
    Sr[k] = U0r*ar.xx - U0i*ai.xx + U1r*ar.yy - U1i*ai.yy;
    Si[k] = U0r*ai.xx + U0i*ar.xx + U1r*ai.yy + U1i*ar.yy;
  }
}

template<int P>
__device__ __forceinline__ void rot_lane(v2f (&Sr)[8], v2f (&Si)[8], const float* m,
                                         int lane, int bpa) {
  const int bit = (lane >> P) & 1;
  const float uar = bit ? m[6] : m[0];
  const float uai = bit ? m[7] : m[1];
  const float ubr = bit ? m[4] : m[2];
  const float ubi = bit ? m[5] : m[3];
#pragma unroll
  for (int k = 0; k < 8; ++k) {
    const v2f ar = Sr[k], ai = Si[k];
    const v2f pr = partner2<P>(ar, bpa), pi = partner2<P>(ai, bpa);
    Sr[k] = uar*ar - uai*ai + ubr*pr - ubi*pi;
    Si[k] = uar*ai + uai*ar + ubr*pi + ubi*pr;
  }
}

// ---- CRY gates (real c = cos(th/2), s = sin(th/2); control==1 applies RY) ----

template<int CB, int J>
__device__ __forceinline__ void cry_reg_reg(v2f (&Sr)[8], v2f (&Si)[8], float c, float s) {
#pragma unroll
  for (int k0 = 0; k0 < 8; ++k0) {
    if ((k0 & J) || !(k0 & CB)) continue;
    const int k1 = k0 | J;
    const v2f a0r=Sr[k0], a0i=Si[k0], a1r=Sr[k1], a1i=Si[k1];
    Sr[k0] = c*a0r - s*a1r;  Si[k0] = c*a0i - s*a1i;
    Sr[k1] = s*a0r + c*a1r;  Si[k1] = s*a0i + c*a1i;
  }
}

// control on packing axis (bit 9), target k-bit 4 (amp bit 8)
__device__ __forceinline__ void cry_axisctrl(v2f (&Sr)[8], v2f (&Si)[8], float c, float s) {
  const v2f cv = {1.0f, c}, sv = {0.0f, s};
#pragma unroll
  for (int k0 = 0; k0 < 4; ++k0) {
    const int k1 = k0 + 4;
    const v2f a0r=Sr[k0], a0i=Si[k0], a1r=Sr[k1], a1i=Si[k1];
    Sr[k0] = cv*a0r - sv*a1r;  Si[k0] = cv*a0i - sv*a1i;
    Sr[k1] = sv*a0r + cv*a1r;  Si[k1] = sv*a0i + cv*a1i;
  }
}

// control k-bit 1 (amp bit 6), target lane bit 5
__device__ __forceinline__ void cry_k0ctrl_lane5(v2f (&Sr)[8], v2f (&Si)[8],
                                                 float c, float s, int lane, int bpa) {
  const float ss = ((lane >> 5) & 1) ? s : -s;
#pragma unroll
  for (int k = 1; k < 8; k += 2) {
    const v2f pr = partner2<5>(Sr[k], bpa), pi = partner2<5>(Si[k], bpa);
    Sr[k] = c*Sr[k] + ss*pr;
    Si[k] = c*Si[k] + ss*pi;
  }
}

template<int PC, int PT>
__device__ __forceinline__ void cry_lane_lane(v2f (&Sr)[8], v2f (&Si)[8],
                                              float c, float s, int lane, int bpa) {
  const bool ctrl = (lane >> PC) & 1;
  const float ce = ctrl ? c : 1.0f;
  const float se = ctrl ? s : 0.0f;
  const float ss = ((lane >> PT) & 1) ? se : -se;
#pragma unroll
  for (int k = 0; k < 8; ++k) {
    const v2f pr = partner2<PT>(Sr[k], bpa), pi = partner2<PT>(Si[k], bpa);
    Sr[k] = ce*Sr[k] + ss*pr;
    Si[k] = ce*Si[k] + ss*pi;
  }
}

// control lane bit 0, target packing axis (bit 9)
__device__ __forceinline__ void cry_lanectrl_axis(v2f (&Sr)[8], v2f (&Si)[8],
                                                  float c, float s, int lane) {
  const bool ctrl = lane & 1;
  const float ce = ctrl ? c : 1.0f;
  const float se = ctrl ? s : 0.0f;
  const v2f sv = {-se, se};
#pragma unroll
  for (int k = 0; k < 8; ++k) {
    const v2f ar = Sr[k], ai = Si[k];
    Sr[k] = ce*ar + sv*ar.yx;
    Si[k] = ce*ai + sv*ai.yx;
  }
}

} // namespace

__global__ __launch_bounds__(256)
void qlayer_kernel(const float* __restrict__ inp,   // (B, 10)
                   const float* __restrict__ wt,    // (80,)
                   float* __restrict__ out,         // (B, 10)
                   int B)
{
  __shared__ float gm[20][8];   // Rot matrices: layer*10+q -> u00,u01,u10,u11 (re,im)
  __shared__ float gc[20][2];   // CRY: cos(th/2), sin(th/2)

  const int tid = threadIdx.x;
  if (tid < 20) {
    // Rot(phi, theta, omega) = RZ(omega) RY(theta) RZ(phi)
    //  = [ c e^{-i a},  -s e^{i b} ]   a = (phi+omega)/2
    //    [ s e^{-i b},   c e^{i a} ]   b = (phi-omega)/2
    const int layer = tid / 10, q = tid % 10;
    const int w = layer * 40 + 3 * q;
    const float phi = wt[w], th = wt[w + 1], om = wt[w + 2];
    float s, c, sa, ca, sb, cb;
    __sincosf(0.5f * th, &s, &c);
    __sincosf(0.5f * (phi + om), &sa, &ca);
    __sincosf(0.5f * (phi - om), &sb, &cb);
    gm[tid][0] =  c * ca;  gm[tid][1] = -c * sa;   // u00
    gm[tid][2] = -s * cb;  gm[tid][3] = -s * sb;   // u01
    gm[tid][4] =  s * cb;  gm[tid][5] = -s * sb;   // u10
    gm[tid][6] =  c * ca;  gm[tid][7] =  c * sa;   // u11
  } else if (tid < 40) {
    const int g = tid - 20;
    const int layer = g / 10, e = g % 10;
    const int w = layer * 40 + 30 + e;
    float s, c;
    __sincosf(0.5f * wt[w], &s, &c);
    gc[g][0] = c;
    gc[g][1] = s;
  }
  __syncthreads();

  const int lane = tid & 63;
  const int bpa = (lane ^ 32) << 2;              // ds_bpermute byte address
  const int sample = (int)((blockIdx.x * (unsigned)blockDim.x + tid) >> 6);
  if (sample >= B) return;

  // ---- init: product state through (embedding RY) + (layer-0 Rot), both
  // single-qubit => amp(idx) = prod_p u_p[bit_p(idx)], u_p complex 2-vec ----
  float fc[10], fs[10];
#pragma unroll
  for (int p = 0; p < 10; ++p) {
    float x = inp[sample * NQB + (9 - p)];
    x = fminf(fmaxf(x, 0.0f), 1.0f);
    __sincosf(1.57079632679489662f * x, &fs[p], &fc[p]);
  }

  // lane factor L = prod_{p=0..5} u_p[lane bit p]
  float Lr = 1.0f, Li = 0.0f;
#pragma unroll
  for (int p = 0; p < 6; ++p) {
    const float* m = &gm[9 - p][0];              // layer 0, qubit q = 9-p
    const bool b = (lane >> p) & 1;
    const float m0 = b ? m[4] : m[0], m1 = b ? m[5] : m[1];
    const float m2 = b ? m[6] : m[2], m3 = b ? m[7] : m[3];
    const float ur = m0 * fc[p] + m2 * fs[p];
    const float ui = m1 * fc[p] + m3 * fs[p];
    if (p == 0) { Lr = ur; Li = ui; }
    else        cmul(Lr, Li, ur, ui);
  }

  // register-factor tree A[k] = L * u6[k&1] * u7[(k>>1)&1] * u8[(k>>2)&1]
  float Ar[8], Ai[8];
  {
    const float* m = &gm[3][0];                  // amp bit 6 -> q=3
    const float u0r = m[0]*fc[6] + m[2]*fs[6], u0i = m[1]*fc[6] + m[3]*fs[6];
    const float u1r = m[4]*fc[6] + m[6]*fs[6], u1i = m[5]*fc[6] + m[7]*fs[6];
    Ar[0] = Lr*u0r - Li*u0i;  Ai[0] = Lr*u0i + Li*u0r;
    Ar[1] = Lr*u1r - Li*u1i;  Ai[1] = Lr*u1i + Li*u1r;
  }
  {
    const float* m = &gm[2][0];                  // amp bit 7 -> q=2
    const float u0r = m[0]*fc[7] + m[2]*fs[7], u0i = m[1]*fc[7] + m[3]*fs[7];
    const float u1r = m[4]*fc[7] + m[6]*fs[7], u1i = m[5]*fc[7] + m[7]*fs[7];
#pragma unroll
    for (int k = 0; k < 2; ++k) {
      Ar[k+2] = Ar[k]*u1r - Ai[k]*u1i;  Ai[k+2] = Ar[k]*u1i + Ai[k]*u1r;
      cmul(Ar[k], Ai[k], u0r, u0i);
    }
  }
  {
    const float* m = &gm[1][0];                  // amp bit 8 -> q=1
    const float u0r = m[0]*fc[8] + m[2]*fs[8], u0i = m[1]*fc[8] + m[3]*fs[8];
    const float u1r = m[4]*fc[8] + m[6]*fs[8], u1i = m[5]*fc[8] + m[7]*fs[8];
#pragma unroll
    for (int k = 0; k < 4; ++k) {
      Ar[k+4] = Ar[k]*u1r - Ai[k]*u1i;  Ai[k+4] = Ar[k]*u1i + Ai[k]*u1r;
      cmul(Ar[k], Ai[k], u0r, u0i);
    }
  }

  v2f Sr[8], Si[8];
  {
    const float* m = &gm[0][0];                  // amp bit 9 (v2f axis) -> q=0
    const v2f u9r = {m[0]*fc[9] + m[2]*fs[9], m[4]*fc[9] + m[6]*fs[9]};
    const v2f u9i = {m[1]*fc[9] + m[3]*fs[9], m[5]*fc[9] + m[7]*fs[9]};
#pragma unroll
    for (int k = 0; k < 8; ++k) {
      Sr[k] = Ar[k]*u9r - Ai[k]*u9i;
      Si[k] = Ar[k]*u9i + Ai[k]*u9r;
    }
  }

  // ---- layer 0: CRY ring only (Rot folded above) ----
  {
    const float (*cc)[2] = &gc[0];
    cry_axisctrl        (Sr, Si, cc[0][0], cc[0][1]);              // (q0,q1) = (p9,p8)
    cry_reg_reg<4, 2>   (Sr, Si, cc[1][0], cc[1][1]);              // (p8,p7)
    cry_reg_reg<2, 1>   (Sr, Si, cc[2][0], cc[2][1]);              // (p7,p6)
    cry_k0ctrl_lane5    (Sr, Si, cc[3][0], cc[3][1], lane, bpa);   // (p6,p5)
    cry_lane_lane<5, 4> (Sr, Si, cc[4][0], cc[4][1], lane, bpa);
    cry_lane_lane<4, 3> (Sr, Si, cc[5][0], cc[5][1], lane, bpa);
    cry_lane_lane<3, 2> (Sr, Si, cc[6][0], cc[6][1], lane, bpa);
    cry_lane_lane<2, 1> (Sr, Si, cc[7][0], cc[7][1], lane, bpa);
    cry_lane_lane<1, 0> (Sr, Si, cc[8][0], cc[8][1], lane, bpa);
    cry_lanectrl_axis   (Sr, Si, cc[9][0], cc[9][1], lane);        // (p0,p9)
  }

  // ---- layer 1: Rot (10) + CRY ring ----
  {
    const float* m = &gm[10][0];
    rot_axis      (Sr, Si, m + 0 * 8);
    rot_reg<4>    (Sr, Si, m + 1 * 8);
    rot_reg<2>    (Sr, Si, m + 2 * 8);
    rot_reg<1>    (Sr, Si, m + 3 * 8);
    rot_lane<5>   (Sr, Si, m + 4 * 8, lane, bpa);
    rot_lane<4>   (Sr, Si, m + 5 * 8, lane, bpa);
    rot_lane<3>   (Sr, Si, m + 6 * 8, lane, bpa);
    rot_lane<2>   (Sr, Si, m + 7 * 8, lane, bpa);
    rot_lane<1>   (Sr, Si, m + 8 * 8, lane, bpa);
    rot_lane<0>   (Sr, Si, m + 9 * 8, lane, bpa);
    const float (*cc)[2] = &gc[10];
    cry_axisctrl        (Sr, Si, cc[0][0], cc[0][1]);
    cry_reg_reg<4, 2>   (Sr, Si, cc[1][0], cc[1][1]);
    cry_reg_reg<2, 1>   (Sr, Si, cc[2][0], cc[2][1]);
    cry_k0ctrl_lane5    (Sr, Si, cc[3][0], cc[3][1], lane, bpa);
    cry_lane_lane<5, 4> (Sr, Si, cc[4][0], cc[4][1], lane, bpa);
    cry_lane_lane<4, 3> (Sr, Si, cc[5][0], cc[5][1], lane, bpa);
    cry_lane_lane<3, 2> (Sr, Si, cc[6][0], cc[6][1], lane, bpa);
    cry_lane_lane<2, 1> (Sr, Si, cc[7][0], cc[7][1], lane, bpa);
    cry_lane_lane<1, 0> (Sr, Si, cc[8][0], cc[8][1], lane, bpa);
    cry_lanectrl_axis   (Sr, Si, cc[9][0], cc[9][1], lane);
  }

  // ---- probabilities and PauliZ expvals ----
  v2f P[8];
#pragma unroll
  for (int k = 0; k < 8; ++k) P[k] = Sr[k]*Sr[k] + Si[k]*Si[k];

  const v2f q01 = P[0]+P[1], q23 = P[2]+P[3], q45 = P[4]+P[5], q67 = P[6]+P[7];
  const v2f h1 = q01+q23, h2 = q45+q67;
  const v2f t2 = h1 + h2;                           // per-lane total (x: bit9=0, y: bit9=1)
  const v2f e8v = h1 - h2;                          // sign on amp bit 8
  const v2f e7v = (q01 - q23) + (q45 - q67);        // sign on amp bit 7
  const v2f d01 = P[0]-P[1], d23 = P[2]-P[3], d45 = P[4]-P[5], d67 = P[6]-P[7];
  const v2f e6v = (d01 + d23) + (d45 + d67);        // sign on amp bit 6

  const float tot = t2.x + t2.y;
  const float o6 = e6v.x + e6v.y;
  const float o7 = e7v.x + e7v.y;
  const float o8 = e8v.x + e8v.y;
  const float o9 = t2.x - t2.y;

  float sgn[6];
#pragma unroll
  for (int p = 0; p < 6; ++p) sgn[p] = ((lane >> p) & 1) ? -1.0f : 1.0f;

  float E[6];
  float t = tot;
#define QSTEP(P)                                             \
  {                                                          \
    const float pt = xorf<P>(t, bpa);                        \
    E[P] = sgn[P] * (t - pt);                                \
    t += pt;                                                 \
    _Pragma("unroll")                                        \
    for (int j = 0; j < P; ++j) E[j] += xorf<P>(E[j], bpa);  \
  }
  QSTEP(0) QSTEP(1) QSTEP(2) QSTEP(3) QSTEP(4) QSTEP(5)
#undef QSTEP

  v2f q1; q1.x = o6; q1.y = o7;
  v2f q2; q2.x = o8; q2.y = o9;
#define RSTEP(P)                   \
  q1 += partner2<P>(q1, bpa);      \
  q2 += partner2<P>(q2, bpa);
  RSTEP(0) RSTEP(1) RSTEP(2) RSTEP(3) RSTEP(4) RSTEP(5)
#undef RSTEP

  // out[sample][q], q = 9 - p:  q=0..3 <- bits 9,8,7,6 ; q=4..9 <- E[5..0]
  if (lane < 10) {
    float v = q2.y;                  // q=0: bit 9
    v = (lane == 1) ? q2.x : v;      // bit 8
    v = (lane == 2) ? q1.y : v;      // bit 7
    v = (lane == 3) ? q1.x : v;      // bit 6
    v = (lane == 4) ? E[5] : v;
    v = (lane == 5) ? E[4] : v;
    v = (lane == 6) ? E[3] : v;
    v = (lane == 7) ? E[2] : v;
    v = (lane == 8) ? E[1] : v;
    v = (lane == 9) ? E[0] : v;
    out[sample * NQB + lane] = v;
  }
}

extern "C" void kernel_launch(void* const* d_in, const int* in_sizes, int n_in,
                              void* d_out, int out_size, void* d_ws, size_t ws_size,
                              hipStream_t stream) {
  const float* inp = (const float*)d_in[0];
  const float* wt  = (const float*)d_in[1];
  float* out = (float*)d_out;
  const int B = in_sizes[0] / NQB;            // 32768
  const int waves_per_block = 4;              // 256 threads
  const int nblocks = (B + waves_per_block - 1) / waves_per_block;
  hipLaunchKernelGGL(qlayer_kernel, dim3(nblocks), dim3(256), 0, stream,
                     inp, wt, out, B);
}

// Round 6
// 120.630 us; speedup vs baseline: 2.3435x; 1.1478x over previous
//
#include <hip/hip_runtime.h>

// 10-qubit batched statevector simulator.
// One wave (64 lanes) per sample. Amp index bits: 0..5 = lane bits,
// 6..8 = k-index bits of v2f arrays, 9 = element (x/y) of each v2f.
// Qubit q (PennyLane wire, MSB-first) lives at amp bit p = 9 - q.
//
// Round-6 changes vs round-5 (VALU-issue-bound at 86% busy):
//  (a) layer-1 Rot factored as D_phi -> real-RY layer -> D_omega, with the
//      wave-uniform (reg/axis) diagonal phases precomputed into LDS and the
//      per-lane phase built as an angle SUM + one sincos. Real RY gates cost
//      half the complex Rot gates. Global phase dropped (probs invariant).
//  (b) XOR-4 partner exchange (the only 2-DPP composition) moved to the DS
//      pipe via ds_swizzle (DS measured ~47% busy, VALU 86%).
//  (c) init trig uses raw v_sin/v_cos in revolutions (x*0.25 is already
//      range-reduced for x in [0,1]); med3 clamp.

namespace {

constexpr int NQB = 10;

typedef float v2f __attribute__((ext_vector_type(2)));

template<int CTRL>
__device__ __forceinline__ float dppf(float x) {
  return __uint_as_float((unsigned)__builtin_amdgcn_update_dpp(
      0, (int)__float_as_uint(x), CTRL, 0xF, 0xF, true));
}

// Partner value x[lane ^ (1<<P)].
// P=0,1,3: single DPP. P=2: ds_swizzle XOR4. P=4: ds_swizzle XOR16.
// P=5: ds_bpermute (addr bpa = (lane^32)<<2).
template<int P>
__device__ __forceinline__ float xorf(float x, int bpa) {
  if constexpr (P == 0) {
    return dppf<0xB1>(x);                       // quad_perm [1,0,3,2] = XOR1
  } else if constexpr (P == 1) {
    return dppf<0x4E>(x);                       // quad_perm [2,3,0,1] = XOR2
  } else if constexpr (P == 2) {
    return __uint_as_float((unsigned)__builtin_amdgcn_ds_swizzle(
        (int)__float_as_uint(x), 0x101F));      // bitmode xor=4
  } else if constexpr (P == 3) {
    return dppf<0x128>(x);                      // row_ror:8 == XOR8 within row16
  } else if constexpr (P == 4) {
    return __uint_as_float((unsigned)__builtin_amdgcn_ds_swizzle(
        (int)__float_as_uint(x), 0x401F));      // bitmode xor=16
  } else {
    return __uint_as_float((unsigned)__builtin_amdgcn_ds_bpermute(
        bpa, (int)__float_as_uint(x)));
  }
}

template<int P>
__device__ __forceinline__ v2f partner2(v2f v, int bpa) {
  v2f r;
  r.x = xorf<P>(v.x, bpa);
  r.y = xorf<P>(v.y, bpa);
  return r;
}

__device__ __forceinline__ float fsin_rev(float rev) {
#if __has_builtin(__builtin_amdgcn_sinf)
  return __builtin_amdgcn_sinf(rev);
#else
  return __sinf(rev * 6.2831853071795864769f);
#endif
}
__device__ __forceinline__ float fcos_rev(float rev) {
#if __has_builtin(__builtin_amdgcn_cosf)
  return __builtin_amdgcn_cosf(rev);
#else
  return __cosf(rev * 6.2831853071795864769f);
#endif
}

__device__ __forceinline__ float clamp01(float x) {
#if __has_builtin(__builtin_amdgcn_fmed3f)
  return __builtin_amdgcn_fmed3f(x, 0.0f, 1.0f);
#else
  return fminf(fmaxf(x, 0.0f), 1.0f);
#endif
}

__device__ __forceinline__ void cmul(float& r, float& i, float br, float bi) {
  const float tr = r * br - i * bi;
  i = r * bi + i * br;
  r = tr;
}

// ---- diagonal layer: S[k] *= e^{i*ang_lane} * RA[k][axis]  (tab = {Rr0,Rr1,Ri0,Ri1} per k)
__device__ __forceinline__ void apply_diag(v2f (&Sr)[8], v2f (&Si)[8],
                                           float ang, const float (*tab)[4]) {
  const float rev = ang * 0.15915494309189535f;
  const float zr = fcos_rev(rev);
  const float zi = fsin_rev(rev);
#pragma unroll
  for (int k = 0; k < 8; ++k) {
    const float4 t4 = *(const float4*)&tab[k][0];
    const v2f Rr = {t4.x, t4.y}, Ri = {t4.z, t4.w};
    const v2f tr = zr*Sr[k] - zi*Si[k];
    const v2f ti = zi*Sr[k] + zr*Si[k];
    Sr[k] = tr*Rr - ti*Ri;
    Si[k] = tr*Ri + ti*Rr;
  }
}

// ---- real RY gates (c = cos(th/2), s = sin(th/2)) ----

__device__ __forceinline__ void ry_axis(v2f (&Sr)[8], v2f (&Si)[8], float c, float s) {
  const v2f sv = {-s, s};
#pragma unroll
  for (int k = 0; k < 8; ++k) {
    const v2f ar = Sr[k], ai = Si[k];
    Sr[k] = c*ar + sv*ar.yx;
    Si[k] = c*ai + sv*ai.yx;
  }
}

template<int J>
__device__ __forceinline__ void ry_reg(v2f (&Sr)[8], v2f (&Si)[8], float c, float s) {
#pragma unroll
  for (int k0 = 0; k0 < 8; ++k0) {
    if (k0 & J) continue;
    const int k1 = k0 | J;
    const v2f a0r=Sr[k0], a0i=Si[k0], a1r=Sr[k1], a1i=Si[k1];
    Sr[k0] = c*a0r - s*a1r;  Si[k0] = c*a0i - s*a1i;
    Sr[k1] = s*a0r + c*a1r;  Si[k1] = s*a0i + c*a1i;
  }
}

template<int P>
__device__ __forceinline__ void ry_lane(v2f (&Sr)[8], v2f (&Si)[8], float c, float s,
                                        int lane, int bpa) {
  const float ss = ((lane >> P) & 1) ? s : -s;
#pragma unroll
  for (int k = 0; k < 8; ++k) {
    const v2f pr = partner2<P>(Sr[k], bpa), pi = partner2<P>(Si[k], bpa);
    Sr[k] = c*Sr[k] + ss*pr;
    Si[k] = c*Si[k] + ss*pi;
  }
}

// ---- CRY gates (real c = cos(th/2), s = sin(th/2); control==1 applies RY) ----

template<int CB, int J>
__device__ __forceinline__ void cry_reg_reg(v2f (&Sr)[8], v2f (&Si)[8], float c, float s) {
#pragma unroll
  for (int k0 = 0; k0 < 8; ++k0) {
    if ((k0 & J) || !(k0 & CB)) continue;
    const int k1 = k0 | J;
    const v2f a0r=Sr[k0], a0i=Si[k0], a1r=Sr[k1], a1i=Si[k1];
    Sr[k0] = c*a0r - s*a1r;  Si[k0] = c*a0i - s*a1i;
    Sr[k1] = s*a0r + c*a1r;  Si[k1] = s*a0i + c*a1i;
  }
}

// control on packing axis (bit 9), target k-bit 4 (amp bit 8)
__device__ __forceinline__ void cry_axisctrl(v2f (&Sr)[8], v2f (&Si)[8], float c, float s) {
  const v2f cv = {1.0f, c}, sv = {0.0f, s};
#pragma unroll
  for (int k0 = 0; k0 < 4; ++k0) {
    const int k1 = k0 + 4;
    const v2f a0r=Sr[k0], a0i=Si[k0], a1r=Sr[k1], a1i=Si[k1];
    Sr[k0] = cv*a0r - sv*a1r;  Si[k0] = cv*a0i - sv*a1i;
    Sr[k1] = sv*a0r + cv*a1r;  Si[k1] = sv*a0i + cv*a1i;
  }
}

// control k-bit 1 (amp bit 6), target lane bit 5
__device__ __forceinline__ void cry_k0ctrl_lane5(v2f (&Sr)[8], v2f (&Si)[8],
                                                 float c, float s, int lane, int bpa) {
  const float ss = ((lane >> 5) & 1) ? s : -s;
#pragma unroll
  for (int k = 1; k < 8; k += 2) {
    const v2f pr = partner2<5>(Sr[k], bpa), pi = partner2<5>(Si[k], bpa);
    Sr[k] = c*Sr[k] + ss*pr;
    Si[k] = c*Si[k] + ss*pi;
  }
}

template<int PC, int PT>
__device__ __forceinline__ void cry_lane_lane(v2f (&Sr)[8], v2f (&Si)[8],
                                              float c, float s, int lane, int bpa) {
  const bool ctrl = (lane >> PC) & 1;
  const float ce = ctrl ? c : 1.0f;
  const float se = ctrl ? s : 0.0f;
  const float ss = ((lane >> PT) & 1) ? se : -se;
#pragma unroll
  for (int k = 0; k < 8; ++k) {
    const v2f pr = partner2<PT>(Sr[k], bpa), pi = partner2<PT>(Si[k], bpa);
    Sr[k] = ce*Sr[k] + ss*pr;
    Si[k] = ce*Si[k] + ss*pi;
  }
}

// control lane bit 0, target packing axis (bit 9)
__device__ __forceinline__ void cry_lanectrl_axis(v2f (&Sr)[8], v2f (&Si)[8],
                                                  float c, float s, int lane) {
  const bool ctrl = lane & 1;
  const float ce = ctrl ? c : 1.0f;
  const float se = ctrl ? s : 0.0f;
  const v2f sv = {-se, se};
#pragma unroll
  for (int k = 0; k < 8; ++k) {
    const v2f ar = Sr[k], ai = Si[k];
    Sr[k] = ce*ar + sv*ar.yx;
    Si[k] = ce*ai + sv*ai.yx;
  }
}

} // namespace

__global__ __launch_bounds__(256)
void qlayer_kernel(const float* __restrict__ inp,   // (B, 10)
                   const float* __restrict__ wt,    // (80,)
                   float* __restrict__ out,         // (B, 10)
                   int B)
{
  __shared__ float gm[10][8];                   // layer-0 Rot matrices
  __shared__ float gc[20][2];                   // CRY cos/sin, both layers
  __shared__ __align__(16) float gdphi[8][4];   // layer-1 D_phi reg/axis phases
  __shared__ __align__(16) float gdome[8][4];   // layer-1 D_omega reg/axis phases
  __shared__ float grot1[10][2];                // layer-1 RY cos/sin

  const int tid = threadIdx.x;
  if (tid < 10) {
    // layer-0 Rot(phi, theta, omega) = RZ(omega) RY(theta) RZ(phi)
    const int w = 3 * tid;
    const float phi = wt[w], th = wt[w + 1], om = wt[w + 2];
    float s, c, sa, ca, sb, cb;
    __sincosf(0.5f * th, &s, &c);
    __sincosf(0.5f * (phi + om), &sa, &ca);
    __sincosf(0.5f * (phi - om), &sb, &cb);
    gm[tid][0] =  c * ca;  gm[tid][1] = -c * sa;   // u00
    gm[tid][2] = -s * cb;  gm[tid][3] = -s * sb;   // u01
    gm[tid][4] =  s * cb;  gm[tid][5] = -s * sb;   // u10
    gm[tid][6] =  c * ca;  gm[tid][7] =  c * sa;   // u11
  } else if (tid < 30) {
    const int g = tid - 10;
    const int layer = g / 10, e = g % 10;
    const int w = layer * 40 + 30 + e;
    float s, c;
    __sincosf(0.5f * wt[w], &s, &c);
    gc[g][0] = c;
    gc[g][1] = s;
  } else if (tid >= 32 && tid < 64) {
    // layer-1 diagonal tables: phase = exp(i * sum_{set reg/axis bits} angle_q)
    // k bit0 <-> q=3, bit1 <-> q=2, bit2 <-> q=1, axis <-> q=0.
    const int t = tid - 32;            // 0..31
    const int dia = t >> 4;            // 0: phi (wt[40+3q]), 1: omega (wt[42+3q])
    const int u = t & 15;
    const int k = u & 7, ax = u >> 3;
    const int base = dia ? 42 : 40;
    float ang = 0.0f;
    if (k & 1) ang += wt[base + 9];
    if (k & 2) ang += wt[base + 6];
    if (k & 4) ang += wt[base + 3];
    if (ax)    ang += wt[base + 0];
    float s, c;
    __sincosf(ang, &s, &c);
    float* gd = dia ? &gdome[0][0] : &gdphi[0][0];
    gd[k * 4 + ax]     = c;
    gd[k * 4 + 2 + ax] = s;
  } else if (tid >= 64 && tid < 74) {
    const int q = tid - 64;
    float s, c;
    __sincosf(0.5f * wt[41 + 3 * q], &s, &c);    // layer-1 theta_q = wt[40+3q+1]
    grot1[q][0] = c;
    grot1[q][1] = s;
  }
  __syncthreads();

  const int lane = tid & 63;
  const int bpa = (lane ^ 32) << 2;              // ds_bpermute byte address
  const int sample = (int)((blockIdx.x * (unsigned)blockDim.x + tid) >> 6);
  if (sample >= B) return;

  // ---- init: product state through (embedding RY) + (layer-0 Rot) ----
  float fc[10], fs[10];
#pragma unroll
  for (int p = 0; p < 10; ++p) {
    const float x = clamp01(inp[sample * NQB + (9 - p)]);
    const float r = 0.25f * x;                   // (pi/2*x) in revolutions
    fs[p] = fsin_rev(r);
    fc[p] = fcos_rev(r);
  }

  // per-lane phase-angle sums for the layer-1 diagonals (lane bit p <-> q=9-p)
  float aphi = 0.0f, aome = 0.0f;
#pragma unroll
  for (int p = 0; p < 6; ++p) {
    const bool b = (lane >> p) & 1;
    aphi += b ? wt[67 - 3 * p] : 0.0f;
    aome += b ? wt[69 - 3 * p] : 0.0f;
  }

  // lane factor L = prod_{p=0..5} u_p[lane bit p],  u_p = Rot_{9-p} (fc,fs)^T
  float Lr = 1.0f, Li = 0.0f;
#pragma unroll
  for (int p = 0; p < 6; ++p) {
    const float* m = &gm[9 - p][0];
    const bool b = (lane >> p) & 1;
    const float m0 = b ? m[4] : m[0], m1 = b ? m[5] : m[1];
    const float m2 = b ? m[6] : m[2], m3 = b ? m[7] : m[3];
    const float ur = m0 * fc[p] + m2 * fs[p];
    const float ui = m1 * fc[p] + m3 * fs[p];
    if (p == 0) { Lr = ur; Li = ui; }
    else        cmul(Lr, Li, ur, ui);
  }

  // register-factor tree A[k] = L * u6[k&1] * u7[(k>>1)&1] * u8[(k>>2)&1]
  float Ar[8], Ai[8];
  {
    const float* m = &gm[3][0];                  // amp bit 6 -> q=3
    const float u0r = m[0]*fc[6] + m[2]*fs[6], u0i = m[1]*fc[6] + m[3]*fs[6];
    const float u1r = m[4]*fc[6] + m[6]*fs[6], u1i = m[5]*fc[6] + m[7]*fs[6];
    Ar[0] = Lr*u0r - Li*u0i;  Ai[0] = Lr*u0i + Li*u0r;
    Ar[1] = Lr*u1r - Li*u1i;  Ai[1] = Lr*u1i + Li*u1r;
  }
  {
    const float* m = &gm[2][0];                  // amp bit 7 -> q=2
    const float u0r = m[0]*fc[7] + m[2]*fs[7], u0i = m[1]*fc[7] + m[3]*fs[7];
    const float u1r = m[4]*fc[7] + m[6]*fs[7], u1i = m[5]*fc[7] + m[7]*fs[7];
#pragma unroll
    for (int k = 0; k < 2; ++k) {
      Ar[k+2] = Ar[k]*u1r - Ai[k]*u1i;  Ai[k+2] = Ar[k]*u1i + Ai[k]*u1r;
      cmul(Ar[k], Ai[k], u0r, u0i);
    }
  }
  {
    const float* m = &gm[1][0];                  // amp bit 8 -> q=1
    const float u0r = m[0]*fc[8] + m[2]*fs[8], u0i = m[1]*fc[8] + m[3]*fs[8];
    const float u1r = m[4]*fc[8] + m[6]*fs[8], u1i = m[5]*fc[8] + m[7]*fs[8];
#pragma unroll
    for (int k = 0; k < 4; ++k) {
      Ar[k+4] = Ar[k]*u1r - Ai[k]*u1i;  Ai[k+4] = Ar[k]*u1i + Ai[k]*u1r;
      cmul(Ar[k], Ai[k], u0r, u0i);
    }
  }

  v2f Sr[8], Si[8];
  {
    const float* m = &gm[0][0];                  // amp bit 9 (v2f axis) -> q=0
    const v2f u9r = {m[0]*fc[9] + m[2]*fs[9], m[4]*fc[9] + m[6]*fs[9]};
    const v2f u9i = {m[1]*fc[9] + m[3]*fs[9], m[5]*fc[9] + m[7]*fs[9]};
#pragma unroll
    for (int k = 0; k < 8; ++k) {
      Sr[k] = Ar[k]*u9r - Ai[k]*u9i;
      Si[k] = Ar[k]*u9i + Ai[k]*u9r;
    }
  }

  // ---- layer 0: CRY ring (Rot folded into init) ----
  {
    const float (*cc)[2] = &gc[0];
    cry_axisctrl        (Sr, Si, cc[0][0], cc[0][1]);              // (p9,p8)
    cry_reg_reg<4, 2>   (Sr, Si, cc[1][0], cc[1][1]);              // (p8,p7)
    cry_reg_reg<2, 1>   (Sr, Si, cc[2][0], cc[2][1]);              // (p7,p6)
    cry_k0ctrl_lane5    (Sr, Si, cc[3][0], cc[3][1], lane, bpa);   // (p6,p5)
    cry_lane_lane<5, 4> (Sr, Si, cc[4][0], cc[4][1], lane, bpa);
    cry_lane_lane<4, 3> (Sr, Si, cc[5][0], cc[5][1], lane, bpa);
    cry_lane_lane<3, 2> (Sr, Si, cc[6][0], cc[6][1], lane, bpa);
    cry_lane_lane<2, 1> (Sr, Si, cc[7][0], cc[7][1], lane, bpa);
    cry_lane_lane<1, 0> (Sr, Si, cc[8][0], cc[8][1], lane, bpa);
    cry_lanectrl_axis   (Sr, Si, cc[9][0], cc[9][1], lane);        // (p0,p9)
  }

  // ---- layer 1: D_phi -> real RY layer -> D_omega -> CRY ring ----
  {
    apply_diag(Sr, Si, aphi, gdphi);
    ry_axis   (Sr, Si, grot1[0][0], grot1[0][1]);          // q=0, axis
    ry_reg<4> (Sr, Si, grot1[1][0], grot1[1][1]);          // q=1, amp bit 8
    ry_reg<2> (Sr, Si, grot1[2][0], grot1[2][1]);          // q=2, amp bit 7
    ry_reg<1> (Sr, Si, grot1[3][0], grot1[3][1]);          // q=3, amp bit 6
    ry_lane<5>(Sr, Si, grot1[4][0], grot1[4][1], lane, bpa);
    ry_lane<4>(Sr, Si, grot1[5][0], grot1[5][1], lane, bpa);
    ry_lane<3>(Sr, Si, grot1[6][0], grot1[6][1], lane, bpa);
    ry_lane<2>(Sr, Si, grot1[7][0], grot1[7][1], lane, bpa);
    ry_lane<1>(Sr, Si, grot1[8][0], grot1[8][1], lane, bpa);
    ry_lane<0>(Sr, Si, grot1[9][0], grot1[9][1], lane, bpa);
    apply_diag(Sr, Si, aome, gdome);

    const float (*cc)[2] = &gc[10];
    cry_axisctrl        (Sr, Si, cc[0][0], cc[0][1]);
    cry_reg_reg<4, 2>   (Sr, Si, cc[1][0], cc[1][1]);
    cry_reg_reg<2, 1>   (Sr, Si, cc[2][0], cc[2][1]);
    cry_k0ctrl_lane5    (Sr, Si, cc[3][0], cc[3][1], lane, bpa);
    cry_lane_lane<5, 4> (Sr, Si, cc[4][0], cc[4][1], lane, bpa);
    cry_lane_lane<4, 3> (Sr, Si, cc[5][0], cc[5][1], lane, bpa);
    cry_lane_lane<3, 2> (Sr, Si, cc[6][0], cc[6][1], lane, bpa);
    cry_lane_lane<2, 1> (Sr, Si, cc[7][0], cc[7][1], lane, bpa);
    cry_lane_lane<1, 0> (Sr, Si, cc[8][0], cc[8][1], lane, bpa);
    cry_lanectrl_axis   (Sr, Si, cc[9][0], cc[9][1], lane);
  }

  // ---- probabilities and PauliZ expvals ----
  v2f P[8];
#pragma unroll
  for (int k = 0; k < 8; ++k) P[k] = Sr[k]*Sr[k] + Si[k]*Si[k];

  const v2f q01 = P[0]+P[1], q23 = P[2]+P[3], q45 = P[4]+P[5], q67 = P[6]+P[7];
  const v2f h1 = q01+q23, h2 = q45+q67;
  const v2f t2 = h1 + h2;                           // per-lane total (x: bit9=0, y: bit9=1)
  const v2f e8v = h1 - h2;                          // sign on amp bit 8
  const v2f e7v = (q01 - q23) + (q45 - q67);        // sign on amp bit 7
  const v2f d01 = P[0]-P[1], d23 = P[2]-P[3], d45 = P[4]-P[5], d67 = P[6]-P[7];
  const v2f e6v = (d01 + d23) + (d45 + d67);        // sign on amp bit 6

  const float tot = t2.x + t2.y;
  const float o6 = e6v.x + e6v.y;
  const float o7 = e7v.x + e7v.y;
  const float o8 = e8v.x + e8v.y;
  const float o9 = t2.x - t2.y;

  float sgn[6];
#pragma unroll
  for (int p = 0; p < 6; ++p) sgn[p] = ((lane >> p) & 1) ? -1.0f : 1.0f;

  float E[6];
  float t = tot;
#define QSTEP(P)                                             \
  {                                                          \
    const float pt = xorf<P>(t, bpa);                        \
    E[P] = sgn[P] * (t - pt);                                \
    t += pt;                                                 \
    _Pragma("unroll")                                        \
    for (int j = 0; j < P; ++j) E[j] += xorf<P>(E[j], bpa);  \
  }
  QSTEP(0) QSTEP(1) QSTEP(2) QSTEP(3) QSTEP(4) QSTEP(5)
#undef QSTEP

  v2f q1; q1.x = o6; q1.y = o7;
  v2f q2; q2.x = o8; q2.y = o9;
#define RSTEP(P)                   \
  q1 += partner2<P>(q1, bpa);      \
  q2 += partner2<P>(q2, bpa);
  RSTEP(0) RSTEP(1) RSTEP(2) RSTEP(3) RSTEP(4) RSTEP(5)
#undef RSTEP

  // out[sample][q], q = 9 - p:  q=0..3 <- bits 9,8,7,6 ; q=4..9 <- E[5..0]
  if (lane < 10) {
    float v = q2.y;                  // q=0: bit 9
    v = (lane == 1) ? q2.x : v;      // bit 8
    v = (lane == 2) ? q1.y : v;      // bit 7
    v = (lane == 3) ? q1.x : v;      // bit 6
    v = (lane == 4) ? E[5] : v;
    v = (lane == 5) ? E[4] : v;
    v = (lane == 6) ? E[3] : v;
    v = (lane == 7) ? E[2] : v;
    v = (lane == 8) ? E[1] : v;
    v = (lane == 9) ? E[0] : v;
    out[sample * NQB + lane] = v;
  }
}

extern "C" void kernel_launch(void* const* d_in, const int* in_sizes, int n_in,
                              void* d_out, int out_size, void* d_ws, size_t ws_size,
                              hipStream_t stream) {
  const float* inp = (const float*)d_in[0];
  const float* wt  = (const float*)d_in[1];
  float* out = (float*)d_out;
  const int B = in_sizes[0] / NQB;            // 32768
  const int waves_per_block = 4;              // 256 threads
  const int nblocks = (B + waves_per_block - 1) / waves_per_block;
  hipLaunchKernelGGL(qlayer_kernel, dim3(nblocks), dim3(256), 0, stream,
                     inp, wt, out, B);
}